// Round 1
// baseline (865.991 us; speedup 1.0000x reference)
//
#include <hip/hip_runtime.h>

// Inverse 2x2 Haar synthesis (IWT).
// Input  x: [B=8, 4*C=256, H=256, W=256] fp32, subband order LL,LH,HL,HH (C=64 each)
// Output o: [B=8, C=64, 2H=512, 2W=512] fp32
// out[b,c,2h+p,2w+q] = 0.25 * (LL +/- LH +/- HL +/- HH) per Haar signs.
//
// Memory-bound: 512 MiB in + 512 MiB out. Each thread: 4 consecutive w
// -> 4x float4 loads (one per subband), 4x float4 stores (2 per output row).

#define B_ 8
#define C_ 64
#define H_ 256
#define W_ 256

__global__ __launch_bounds__(256) void iwt_kernel(const float* __restrict__ x,
                                                  float* __restrict__ out) {
    const int tid = blockIdx.x * 256 + threadIdx.x;   // 0 .. 8*64*256*64-1
    const int w4 = tid & 63;           // w/4  (64 groups of 4 along W)
    const int h  = (tid >> 6) & 255;
    const int c  = (tid >> 14) & 63;
    const int b  = tid >> 20;

    const int HW      = H_ * W_;            // 65536
    const int kstride = C_ * HW;            // 4,194,304 (one subband block)
    const int in_base = b * (4 * kstride) + c * HW + h * W_ + (w4 << 2);

    const float4 ll = *(const float4*)(x + in_base);
    const float4 lh = *(const float4*)(x + in_base + kstride);
    const float4 hl = *(const float4*)(x + in_base + 2 * kstride);
    const float4 hh = *(const float4*)(x + in_base + 3 * kstride);

    float4 r0a, r0b, r1a, r1b;
    float u, v, p, q;
#define HAAR1(A, Bv, Cv, D, O00, O01, O10, O11)        \
    u = (A) + (Bv); v = (A) - (Bv);                    \
    p = (Cv) + (D); q = (Cv) - (D);                    \
    O00 = (u + p) * 0.25f; O01 = (u - p) * 0.25f;      \
    O10 = (v + q) * 0.25f; O11 = (v - q) * 0.25f;

    HAAR1(ll.x, lh.x, hl.x, hh.x, r0a.x, r0a.y, r1a.x, r1a.y)
    HAAR1(ll.y, lh.y, hl.y, hh.y, r0a.z, r0a.w, r1a.z, r1a.w)
    HAAR1(ll.z, lh.z, hl.z, hh.z, r0b.x, r0b.y, r1b.x, r1b.y)
    HAAR1(ll.w, lh.w, hl.w, hh.w, r0b.z, r0b.w, r1b.z, r1b.w)
#undef HAAR1

    // Output: [B, C, 512, 512]; rows 2h and 2h+1, columns 8*w4 .. 8*w4+7
    const int out_row0 = ((b * C_ + c) * (2 * H_) + 2 * h) * (2 * W_) + (w4 << 3);
    *(float4*)(out + out_row0)           = r0a;
    *(float4*)(out + out_row0 + 4)       = r0b;
    *(float4*)(out + out_row0 + 2 * W_)      = r1a;
    *(float4*)(out + out_row0 + 2 * W_ + 4)  = r1b;
}

extern "C" void kernel_launch(void* const* d_in, const int* in_sizes, int n_in,
                              void* d_out, int out_size, void* d_ws, size_t ws_size,
                              hipStream_t stream) {
    const float* x = (const float*)d_in[0];
    float* out = (float*)d_out;
    const int total_threads = B_ * C_ * H_ * (W_ / 4);   // 8,388,608
    const int block = 256;
    const int grid = total_threads / block;              // 32768
    iwt_kernel<<<grid, block, 0, stream>>>(x, out);
}